// Round 3
// baseline (1217.169 us; speedup 1.0000x reference)
//
#include <hip/hip_runtime.h>

// OnlineDenoisingAutoencoder: LSTM(B=2048, T=2048, in=1, proj=16, H=32)
// R9: K-split across wave halves. 1 batch/wave (2048 waves -> 2/SIMD), lane =
// (j = lane&31 hidden index, khalf = lane>>5 dot k-half). Each lane computes
// all 4 gates for its j but dots only 16 of the 32 h values -> 32 fdot2/step
// (R6: 64; R7: 64 at 1 batch/wave). Gate partials merged across halves with
// permlane32_swap + symmetric r[0]+r[1] add (convention-free, proven R7);
// x/bias constants zeroed on khalf1 so the merge doesn't double-count.
// h all-gather: half-size register butterfly (R8's proven within-16-row DPP
// pack tree -> 8 slots) + one permlane16_swap level; W_hh loaded in slot
// order via the identical index butterfly (R8-proven trick), and the slot
// selection picks whichever swap result has index-range == khalf, so
// coverage across partner lanes is structurally guaranteed regardless of
// the instruction's return-pair convention. Zero memory ops in the
// recurrence chain. Output reduce: R6-proven 5-level DPP, writer lane 31.
// History: R6 665us (271 instr-cyc/batch, 1/SIMD, 237 stall); R7 796us
// (2/SIMD works but +40% per-batch fixed cost); R8 728us (LDS removal only
// recovered 78 cyc stall, butterfly cost +152 issue).

#define BB 2048
#define TT 2048
#define HH 32

typedef _Float16 h2 __attribute__((ext_vector_type(2)));
typedef unsigned int uint2v __attribute__((ext_vector_type(2)));

__device__ __forceinline__ float gate_eval(float x, float m, float a, float b) {
    // a * (1 / (1 + 2^(m*x))) + b ; sigmoid: m=-log2e,a=1,b=0 ; tanh: m=-2log2e,a=2,b=-1
    float e = __builtin_amdgcn_exp2f(x * m);
    float r = __builtin_amdgcn_rcpf(1.0f + e);
    return fmaf(a, r, b);
}

template <int CTRL>
__device__ __forceinline__ int dpp_i(int v) {
    return __builtin_amdgcn_update_dpp(0, v, CTRL, 0xf, 0xf, true);
}

template <int CTRL>
__device__ __forceinline__ float dpp_add(float v) {
    int s = __builtin_amdgcn_update_dpp(0, __float_as_int(v), CTRL, 0xf, 0xf, true);
    return v + __int_as_float(s);
}

#define DPP_XOR1 0xB1   // quad_perm [1,0,3,2]
#define DPP_XOR2 0x4E   // quad_perm [2,3,0,1]
#define DPP_ROR4 0x124  // row_ror:4
#define DPP_ROR8 0x128  // row_ror:8

// Exchange between even/odd 16-lane rows. Returns the two row values in
// (r0, r1); per-lane meaning of r0/r1 is absorbed by the index-mirroring
// at init, so only "the pair covers both rows" is assumed.
__device__ __forceinline__ void rowswap16(unsigned q, unsigned &r0, unsigned &r1) {
#if __has_builtin(__builtin_amdgcn_permlane16_swap)
    uint2v r = __builtin_amdgcn_permlane16_swap(q, q, false, false);
    r0 = r[0]; r1 = r[1];
#else
    r0 = q;
    r1 = (unsigned)__builtin_amdgcn_ds_swizzle((int)q, 0x401F); // lane ^ 16
#endif
}

__global__ __launch_bounds__(256) void lstm_fused_kernel(
    const float* __restrict__ x_seq,  // [B,T,1]
    const float* __restrict__ Wp,     // [16,1]
    const float* __restrict__ bp,     // [16]
    const float* __restrict__ W_ih,   // [128,16]
    const float* __restrict__ W_hh,   // [128,32]
    const float* __restrict__ b_ih,   // [128]
    const float* __restrict__ b_hh,   // [128]
    const float* __restrict__ Wo,     // [1,32]
    const float* __restrict__ bo,     // [1]
    float* __restrict__ out)          // [B,T,1] fp32
{
    const int tid  = threadIdx.x;
    const int wave = tid >> 6;
    const int lane = tid & 63;
    const int j    = lane & 31;                 // hidden index this lane owns
    const unsigned khalf = (unsigned)(lane >> 5); // which 16-wide k-half this lane dots
    const int b    = blockIdx.x * 4 + wave;     // one batch element per wave

    // PyTorch gate row order: i=[0,32), f=[32,64), g=[64,96), o=[96,128)
    const int rI = j, rF = HH + j, rG = 2 * HH + j, rO = 3 * HH + j;

    // ---- index butterfly: which h-index lands in each slot of each lane ----
    // (identical op sequence to the per-step value butterfly below)
    int iL0 = j;
    int iH0 = dpp_i<DPP_XOR1>(iL0);
    int iL1 = dpp_i<DPP_XOR2>(iL0), iH1 = dpp_i<DPP_XOR2>(iH0);
    int iL2 = dpp_i<DPP_ROR4>(iL0), iH2 = dpp_i<DPP_ROR4>(iH0);
    int iL3 = dpp_i<DPP_ROR4>(iL1), iH3 = dpp_i<DPP_ROR4>(iH1);
    int iL4 = dpp_i<DPP_ROR8>(iL0), iH4 = dpp_i<DPP_ROR8>(iH0);
    int iL5 = dpp_i<DPP_ROR8>(iL1), iH5 = dpp_i<DPP_ROR8>(iH1);
    int iL6 = dpp_i<DPP_ROR8>(iL2), iH6 = dpp_i<DPP_ROR8>(iH2);
    int iL7 = dpp_i<DPP_ROR8>(iL3), iH7 = dpp_i<DPP_ROR8>(iH3);

    int selL[8], selH[8];
    unsigned use0;
    {
        const int tL[8] = {iL0, iL1, iL2, iL3, iL4, iL5, iL6, iL7};
        const int tH[8] = {iH0, iH1, iH2, iH3, iH4, iH5, iH6, iH7};
        unsigned eL[8], oL[8], eH[8], oH[8];
#pragma unroll
        for (int p = 0; p < 8; ++p) {
            rowswap16((unsigned)tL[p], eL[p], oL[p]);
            rowswap16((unsigned)tH[p], eH[p], oH[p]);
        }
        // pick the swap result whose index-range (bit4) matches our k-half;
        // exactly one of the pair does, so partner lanes (lane^32, khalf
        // flipped) are guaranteed to cover the complementary 16 indices.
        use0 = (((eL[0] >> 4) & 1u) == khalf) ? 1u : 0u;
#pragma unroll
        for (int p = 0; p < 8; ++p) {
            selL[p] = use0 ? (int)eL[p] : (int)oL[p];
            selH[p] = use0 ? (int)eH[p] : (int)oH[p];
        }
    }

    // ---- W_hh rows (4 gates) loaded in butterfly slot order, fp16-packed ----
    h2 wI[8], wF[8], wG[8], wO[8];
    {
        const float* WI = W_hh + rI * HH;
        const float* WF = W_hh + rF * HH;
        const float* WG = W_hh + rG * HH;
        const float* WO = W_hh + rO * HH;
#pragma unroll
        for (int p = 0; p < 8; ++p) {
            wI[p].x = (_Float16)WI[selL[p]]; wI[p].y = (_Float16)WI[selH[p]];
            wF[p].x = (_Float16)WF[selL[p]]; wF[p].y = (_Float16)WF[selH[p]];
            wG[p].x = (_Float16)WG[selL[p]]; wG[p].y = (_Float16)WG[selH[p]];
            wO[p].x = (_Float16)WO[selL[p]]; wO[p].y = (_Float16)WO[selH[p]];
        }
    }

    // ---- collapse input pipeline: gate pre-act = dot + x*a + c (INPUT_DIM==1)
    // khalf1 lanes zero their constant/x terms so the symmetric cross-half
    // merge doesn't double-count them.
    float aI = 0.f, cI = 0.f, aF = 0.f, cF = 0.f;
    float aG = 0.f, cG = 0.f, aO = 0.f, cO = 0.f;
#pragma unroll
    for (int p = 0; p < 16; ++p) {
        float wpv = Wp[p], bpv = bp[p];
        float wi = W_ih[rI * 16 + p], wf = W_ih[rF * 16 + p];
        float wg = W_ih[rG * 16 + p], wo_ = W_ih[rO * 16 + p];
        aI = fmaf(wi, wpv, aI);  cI = fmaf(wi, bpv, cI);
        aF = fmaf(wf, wpv, aF);  cF = fmaf(wf, bpv, cF);
        aG = fmaf(wg, wpv, aG);  cG = fmaf(wg, bpv, cG);
        aO = fmaf(wo_, wpv, aO); cO = fmaf(wo_, bpv, cO);
    }
    cI += b_ih[rI] + b_hh[rI];
    cF += b_ih[rF] + b_hh[rF];
    cG += b_ih[rG] + b_hh[rG];
    cO += b_ih[rO] + b_hh[rO];
    if (khalf) {
        aI = 0.f; cI = 0.f; aF = 0.f; cF = 0.f;
        aG = 0.f; cG = 0.f; aO = 0.f; cO = 0.f;
    }

    const float LOG2E = 1.44269504088896340736f;
    const float woj = Wo[j];
    const float bo0 = bo[0];

    // slot buffers for the gathered h k-half (packed fp16 pairs); h0=0 -> zeros
    unsigned m[8];
#pragma unroll
    for (int p = 0; p < 8; ++p) m[p] = 0u;

    float c = 0.0f;
    const float* xp = x_seq + (size_t)b * TT;
    float* op = out + (size_t)b * TT;

    float4 x4 = *(const float4*)(xp);

    for (int t = 0; t < TT; t += 4) {
        const int tn = (t + 4 < TT) ? (t + 4) : t;
        float4 x4n = *(const float4*)(xp + tn);   // prefetch next group
        float outv[4];
#pragma unroll
        for (int u = 0; u < 4; ++u) {
            float xv = (u == 0) ? x4.x : (u == 1) ? x4.y : (u == 2) ? x4.z : x4.w;

            // 4 half-dots over this lane's 16 h values (8 slots), 2 accums each
            float sI0 = cI, sI1 = xv * aI;
            float sF0 = cF, sF1 = xv * aF;
            float sG0 = cG, sG1 = xv * aG;
            float sO0 = cO, sO1 = xv * aO;
#pragma unroll
            for (int p = 0; p < 8; p += 2) {
                h2 h0 = __builtin_bit_cast(h2, m[p]);
                h2 h1 = __builtin_bit_cast(h2, m[p + 1]);
                sI0 = __builtin_amdgcn_fdot2(wI[p],     h0, sI0, false);
                sF0 = __builtin_amdgcn_fdot2(wF[p],     h0, sF0, false);
                sG0 = __builtin_amdgcn_fdot2(wG[p],     h0, sG0, false);
                sO0 = __builtin_amdgcn_fdot2(wO[p],     h0, sO0, false);
                sI1 = __builtin_amdgcn_fdot2(wI[p + 1], h1, sI1, false);
                sF1 = __builtin_amdgcn_fdot2(wF[p + 1], h1, sF1, false);
                sG1 = __builtin_amdgcn_fdot2(wG[p + 1], h1, sG1, false);
                sO1 = __builtin_amdgcn_fdot2(wO[p + 1], h1, sO1, false);
            }

            // cross-half merge: total = own partial + partner partial.
            // r[0]+r[1] is symmetric in the pair -> convention-independent.
            float pI = sI0 + sI1, pF = sF0 + sF1, pG = sG0 + sG1, pO = sO0 + sO1;
            uint2v mI = __builtin_amdgcn_permlane32_swap(
                __float_as_uint(pI), __float_as_uint(pI), false, false);
            uint2v mF = __builtin_amdgcn_permlane32_swap(
                __float_as_uint(pF), __float_as_uint(pF), false, false);
            uint2v mG = __builtin_amdgcn_permlane32_swap(
                __float_as_uint(pG), __float_as_uint(pG), false, false);
            uint2v mO = __builtin_amdgcn_permlane32_swap(
                __float_as_uint(pO), __float_as_uint(pO), false, false);
            float gI = __uint_as_float(mI[0]) + __uint_as_float(mI[1]);
            float gF = __uint_as_float(mF[0]) + __uint_as_float(mF[1]);
            float gG = __uint_as_float(mG[0]) + __uint_as_float(mG[1]);
            float gO = __uint_as_float(mO[0]) + __uint_as_float(mO[1]);

            float iv = gate_eval(gI, -LOG2E, 1.0f, 0.0f);
            float fv = gate_eval(gF, -LOG2E, 1.0f, 0.0f);
            float gv = gate_eval(gG, -2.0f * LOG2E, 2.0f, -1.0f);
            float ov = gate_eval(gO, -LOG2E, 1.0f, 0.0f);

            c = fmaf(fv, c, iv * gv);
            float th = gate_eval(c, -2.0f * LOG2E, 2.0f, -1.0f); // tanh(c)
            float h = ov * th;

            // ---- half-size register butterfly: gather this lane's k-half ----
            unsigned own = (unsigned)__builtin_bit_cast(unsigned short, (_Float16)h);
            int nb = dpp_i<DPP_XOR1>((int)own);
            unsigned q0 = own | ((unsigned)nb << 16);
            unsigned q1 = (unsigned)dpp_i<DPP_XOR2>((int)q0);
            unsigned q2 = (unsigned)dpp_i<DPP_ROR4>((int)q0);
            unsigned q3 = (unsigned)dpp_i<DPP_ROR4>((int)q1);
            unsigned q4 = (unsigned)dpp_i<DPP_ROR8>((int)q0);
            unsigned q5 = (unsigned)dpp_i<DPP_ROR8>((int)q1);
            unsigned q6 = (unsigned)dpp_i<DPP_ROR8>((int)q2);
            unsigned q7 = (unsigned)dpp_i<DPP_ROR8>((int)q3);
            {
                unsigned r0, r1;
                rowswap16(q0, r0, r1); m[0] = use0 ? r0 : r1;
                rowswap16(q1, r0, r1); m[1] = use0 ? r0 : r1;
                rowswap16(q2, r0, r1); m[2] = use0 ? r0 : r1;
                rowswap16(q3, r0, r1); m[3] = use0 ? r0 : r1;
                rowswap16(q4, r0, r1); m[4] = use0 ? r0 : r1;
                rowswap16(q5, r0, r1); m[5] = use0 ? r0 : r1;
                rowswap16(q6, r0, r1); m[6] = use0 ? r0 : r1;
                rowswap16(q7, r0, r1); m[7] = use0 ? r0 : r1;
            }

            // fused output projection (R6-proven): row_shr 1/2/4/8 then
            // row_bcast15 -> total lands in lane 31 (and 63, unused).
            float po = woj * h;
            po = dpp_add<0x111>(po);
            po = dpp_add<0x112>(po);
            po = dpp_add<0x114>(po);
            po = dpp_add<0x118>(po);
            po = dpp_add<0x142>(po);
            outv[u] = po + bo0;
        }
        if (lane == 31) {
            *(float4*)(op + t) = make_float4(outv[0], outv[1], outv[2], outv[3]);
        }
        x4 = x4n;
    }
}

extern "C" void kernel_launch(void* const* d_in, const int* in_sizes, int n_in,
                              void* d_out, int out_size, void* d_ws, size_t ws_size,
                              hipStream_t stream) {
    const float* x_seq = (const float*)d_in[0];
    const float* Wp    = (const float*)d_in[1];
    const float* bp    = (const float*)d_in[2];
    const float* W_ih  = (const float*)d_in[3];
    const float* W_hh  = (const float*)d_in[4];
    const float* b_ih  = (const float*)d_in[5];
    const float* b_hh  = (const float*)d_in[6];
    const float* Wo    = (const float*)d_in[7];
    const float* bo    = (const float*)d_in[8];
    float* out = (float*)d_out;

    dim3 grid(BB / 4);   // 4 waves/block, 1 batch/wave -> 2048 waves (2/SIMD)
    dim3 block(256);
    lstm_fused_kernel<<<grid, block, 0, stream>>>(
        x_seq, Wp, bp, W_ih, W_hh, b_ih, b_hh, Wo, bo, out);
}

// Round 4
// 760.302 us; speedup vs baseline: 1.6009x; 1.6009x over previous
//
#include <hip/hip_runtime.h>

// OnlineDenoisingAutoencoder: LSTM(B=2048, T=2048, in=1, proj=16, H=32)
// R10 = R7 (gate-split, 1 batch/wave, 2 waves/SIMD) + anti-phase stagger.
// R7's counters are self-consistent with PHASE-LOCKED SIMD-mates: wall/step
// 932 cyc, per-wave issue 348, busy 2*348/932 = 74.7% == measured 74.6%.
// Both waves run identical code from the same start time; interleaved issue
// keeps them aligned, so both stall on the latency tail (trans chain + LDS
// round trip) simultaneously -> 25% idle with 2 resident waves. The
// anti-phase fixed point (one wave's fdot2 burst covers the other's tail)
// is issue-bound: wall ~= 696 cyc/step -> ~594us. We seed it with a
// one-time ~320-cyc s_sleep on odd HW_ID.WAVE_ID slots (co-resident waves
// on a SIMD always occupy different slots, so this is placement-robust).
// Everything else is bit-identical to R7 (proven numerics, absmax 9.8e-4).
// History: R6 665us (2 batch/wave, 1/SIMD, 237 stall); R7 796us (2/SIMD,
// phase-locked, busy 74.6%); R8 728us (reg butterfly: -78 stall +152 issue);
// R9 1264us (K-split: exchange machinery ~3x static cost). Lesson: LDS
// broadcast (5 DS ops) is the cheapest all-gather; register exchange costs
// 2-3x its static count on gfx950.

#define BB 2048
#define TT 2048
#define HH 32

typedef _Float16 h2 __attribute__((ext_vector_type(2)));
typedef unsigned int uint2v __attribute__((ext_vector_type(2)));

__device__ __forceinline__ float gate_eval(float x, float m, float a, float b) {
    // a * (1 / (1 + 2^(m*x))) + b ; sigmoid: m=-log2e,a=1,b=0 ; tanh: m=-2log2e,a=2,b=-1
    float e = __builtin_amdgcn_exp2f(x * m);
    float r = __builtin_amdgcn_rcpf(1.0f + e);
    return fmaf(a, r, b);
}

template <int CTRL>
__device__ __forceinline__ float dpp_add(float v) {
    int s = __builtin_amdgcn_update_dpp(0, __float_as_int(v), CTRL, 0xf, 0xf, true);
    return v + __int_as_float(s);
}

struct HVec { h2 v[16]; };

__device__ __forceinline__ HVec gather_h(const _Float16* base) {
    const float4* p = (const float4*)base;   // 64 B = 4 x ds_read_b128 (broadcast)
    float4 q0 = p[0], q1 = p[1], q2 = p[2], q3 = p[3];
    HVec r;
    r.v[0]  = __builtin_bit_cast(h2, q0.x); r.v[1]  = __builtin_bit_cast(h2, q0.y);
    r.v[2]  = __builtin_bit_cast(h2, q0.z); r.v[3]  = __builtin_bit_cast(h2, q0.w);
    r.v[4]  = __builtin_bit_cast(h2, q1.x); r.v[5]  = __builtin_bit_cast(h2, q1.y);
    r.v[6]  = __builtin_bit_cast(h2, q1.z); r.v[7]  = __builtin_bit_cast(h2, q1.w);
    r.v[8]  = __builtin_bit_cast(h2, q2.x); r.v[9]  = __builtin_bit_cast(h2, q2.y);
    r.v[10] = __builtin_bit_cast(h2, q2.z); r.v[11] = __builtin_bit_cast(h2, q2.w);
    r.v[12] = __builtin_bit_cast(h2, q3.x); r.v[13] = __builtin_bit_cast(h2, q3.y);
    r.v[14] = __builtin_bit_cast(h2, q3.z); r.v[15] = __builtin_bit_cast(h2, q3.w);
    return r;
}

__global__ __launch_bounds__(256) void lstm_fused_kernel(
    const float* __restrict__ x_seq,  // [B,T,1]
    const float* __restrict__ Wp,     // [16,1]
    const float* __restrict__ bp,     // [16]
    const float* __restrict__ W_ih,   // [128,16]
    const float* __restrict__ W_hh,   // [128,32]
    const float* __restrict__ b_ih,   // [128]
    const float* __restrict__ b_hh,   // [128]
    const float* __restrict__ Wo,     // [1,32]
    const float* __restrict__ bo,     // [1]
    float* __restrict__ out)          // [B,T,1] fp32
{
    const int tid  = threadIdx.x;
    const int wave = tid >> 6;
    const int lane = tid & 63;
    const int half = lane >> 5;      // gate-pair selector: 0 -> (i,g), 1 -> (f,o)
    const int j    = lane & 31;      // hidden index this lane owns
    const int b    = blockIdx.x * 4 + wave;   // one batch element per wave

    // PyTorch gate row order: i=[0,32), f=[32,64), g=[64,96), o=[96,128)
    const int rA = half * HH + j;            // i (half0) or f (half1) -- sigmoid
    const int rB = 2 * HH + half * HH + j;   // g (half0, tanh) or o (half1, sigmoid)

    // ---- W_hh rows (2 gates per lane) into registers as packed fp16 pairs ----
    h2 wA[16], wB[16];
    {
        const float2* pA = (const float2*)(W_hh + rA * HH);
        const float2* pB = (const float2*)(W_hh + rB * HH);
#pragma unroll
        for (int k = 0; k < 16; ++k) {
            float2 a = pA[k], q = pB[k];
            wA[k].x = (_Float16)a.x; wA[k].y = (_Float16)a.y;
            wB[k].x = (_Float16)q.x; wB[k].y = (_Float16)q.y;
        }
    }

    // ---- collapse input pipeline: gate pre-act = dot + x*xA + kA (INPUT_DIM==1) ----
    float xA = 0.f, kA = 0.f, xB = 0.f, kB = 0.f;
#pragma unroll
    for (int p = 0; p < 16; ++p) {
        float wpv = Wp[p], bpv = bp[p];
        float wa = W_ih[rA * 16 + p], wb = W_ih[rB * 16 + p];
        xA = fmaf(wa, wpv, xA);  kA = fmaf(wa, bpv, kA);
        xB = fmaf(wb, wpv, xB);  kB = fmaf(wb, bpv, kB);
    }
    kA += b_ih[rA] + b_hh[rA];
    kB += b_ih[rB] + b_hh[rB];

    const float LOG2E = 1.44269504088896340736f;
    // per-lane gate-B nonlinearity constants: tanh (half0) vs sigmoid (half1)
    const float mB = half ? -LOG2E : -2.0f * LOG2E;
    const float aB = half ? 1.0f   : 2.0f;
    const float bB = half ? 0.0f   : -1.0f;

    const float woj = Wo[j];
    const float bo0 = bo[0];

    // per-(wave,half) h replica, fp16, 64 B each (h identical across halves)
    __shared__ __align__(16) _Float16 hsh[4][2][HH];
    _Float16* hbase = &hsh[wave][half][0];
    hbase[j] = (_Float16)0.0f;

    float c = 0.0f;
    const float* xp = x_seq + (size_t)b * TT;
    float* op = out + (size_t)b * TT;

    HVec hcur = gather_h(hbase);            // zeros (same-wave DS order)
    float4 x4 = *(const float4*)(xp);

    // ---- anti-phase stagger: odd wave-slots on each SIMD delay ~320 cyc ----
    // HW_ID (hwreg id 4), WAVE_ID field = bits [3:0]; co-resident waves on a
    // SIMD occupy distinct slots, so slot parity differs for SIMD-mates.
    // imm encoding: id | (offset<<6) | ((size-1)<<11) = 4 | 0 | (3<<11) = 6148.
    {
        unsigned slot = __builtin_amdgcn_s_getreg(6148);
        if (slot & 1) __builtin_amdgcn_s_sleep(5);   // ~5*64 = 320 cycles
    }

    for (int t = 0; t < TT; t += 4) {
        const int tn = (t + 4 < TT) ? (t + 4) : t;
        float4 x4n = *(const float4*)(xp + tn);   // prefetch next group
        float outv[4];
#pragma unroll
        for (int u = 0; u < 4; ++u) {
            float xv = (u == 0) ? x4.x : (u == 1) ? x4.y : (u == 2) ? x4.z : x4.w;

            // 2 gate dots over h (fp16 inputs, fp32 accum), 2 accumulators each
            float sA0 = kA, sA1 = xv * xA;
            float sB0 = kB, sB1 = xv * xB;
#pragma unroll
            for (int k = 0; k < 16; k += 2) {
                h2 h0 = hcur.v[k], h1 = hcur.v[k + 1];
                sA0 = __builtin_amdgcn_fdot2(wA[k],     h0, sA0, false);
                sB0 = __builtin_amdgcn_fdot2(wB[k],     h0, sB0, false);
                sA1 = __builtin_amdgcn_fdot2(wA[k + 1], h1, sA1, false);
                sB1 = __builtin_amdgcn_fdot2(wB[k + 1], h1, sB1, false);
            }

            float Aact = gate_eval(sA0 + sA1, -LOG2E, 1.0f, 0.0f);  // sigmoid(i|f)
            float Bact = gate_eval(sB0 + sB1, mB, aB, bB);          // tanh(g)|sigmoid(o)

            // cross-half all-broadcast: r[0] = lower-half value in both halves,
            // r[1] = upper-half value in both halves (v_permlane32_swap_b32)
            uint2v eA = __builtin_amdgcn_permlane32_swap(
                __float_as_uint(Aact), __float_as_uint(Aact), false, false);
            uint2v eB = __builtin_amdgcn_permlane32_swap(
                __float_as_uint(Bact), __float_as_uint(Bact), false, false);
            float iv = __uint_as_float(eA[0]);   // sigmoid(i)
            float fv = __uint_as_float(eA[1]);   // sigmoid(f)
            float gv = __uint_as_float(eB[0]);   // tanh(g)
            float ov = __uint_as_float(eB[1]);   // sigmoid(o)

            c = fmaf(fv, c, iv * gv);
            float th = gate_eval(c, -2.0f * LOG2E, 2.0f, -1.0f); // tanh(c)
            float h = ov * th;

            // publish h (both halves write identical value to their own replica),
            // then issue next gather; DPP reduce below overlaps the LDS latency
            hbase[j] = (_Float16)h;
            hcur = gather_h(hbase);

            // fused output projection: width-32 reduce on VALU via DPP.
            // row_shr 1/2/4/8 then row_bcast15 -> total lands in lane 31.
            float po = woj * h;
            po = dpp_add<0x111>(po);
            po = dpp_add<0x112>(po);
            po = dpp_add<0x114>(po);
            po = dpp_add<0x118>(po);
            po = dpp_add<0x142>(po);
            outv[u] = po + bo0;
        }
        if (lane == 31) {
            *(float4*)(op + t) = make_float4(outv[0], outv[1], outv[2], outv[3]);
        }
        x4 = x4n;
    }
}

extern "C" void kernel_launch(void* const* d_in, const int* in_sizes, int n_in,
                              void* d_out, int out_size, void* d_ws, size_t ws_size,
                              hipStream_t stream) {
    const float* x_seq = (const float*)d_in[0];
    const float* Wp    = (const float*)d_in[1];
    const float* bp    = (const float*)d_in[2];
    const float* W_ih  = (const float*)d_in[3];
    const float* W_hh  = (const float*)d_in[4];
    const float* b_ih  = (const float*)d_in[5];
    const float* b_hh  = (const float*)d_in[6];
    const float* Wo    = (const float*)d_in[7];
    const float* bo    = (const float*)d_in[8];
    float* out = (float*)d_out;

    dim3 grid(BB / 4);   // 4 waves/block, 1 batch/wave -> 2048 waves (2/SIMD)
    dim3 block(256);
    lstm_fused_kernel<<<grid, block, 0, stream>>>(
        x_seq, Wp, bp, W_ih, W_hh, b_ih, b_hh, Wo, bo, out);
}